// Round 9
// baseline (26.838 us; speedup 1.0000x reference)
//
#include <hip/hip_runtime.h>

// RoPE with position gather — fused, output-streaming, 1x-replication,
// 32-deep load window (latency-depth probe).
// x:    [B=4, H=16, S=2048, D=128] f32
// rope: [4096, 128, 128] f32 (only the 2x2 rotation diagonals are read)
// tp:   [2048] int32;  out[b,h,s,:] = rotate(x[b,h,p,:], angles(p)), p=tp[s]
//
// 65536 threads (512 x 128): thread owns ONE unique (s, q), iterates all 64
// bh slices. cs float2 loads: exactly 1 request per distinct (p,i) value
// (128K total, minimum w/o cross-thread sharing). Writes perfectly
// streaming nt-stores. unroll 32 -> up to 32 independent gathered float4
// loads in flight per thread (vs 16 in R8) to probe latency-boundedness.

#define SEQL 2048
#define DK   128
#define BLK  128
#define NBLK 512
#define ITER 64            // all bh slices per thread

typedef float vfloat4 __attribute__((ext_vector_type(4)));

__global__ __launch_bounds__(BLK) void rope_fused_kernel(
        const float* __restrict__ x,
        const float* __restrict__ rope,
        const int* __restrict__ tp,
        float* __restrict__ out) {
    const int idx0 = blockIdx.x * BLK + threadIdx.x;   // = s*32 + q, unique
    const int q    = idx0 & 31;            // float4-quad within 128-elem row
    const int s    = idx0 >> 5;            // 0..2047
    const int p    = tp[s];

    const float* rp = rope + (size_t)p * (DK * DK);
    const int i0 = q << 1;
    const float2 cs0 = *reinterpret_cast<const float2*>(rp + (size_t)258 * i0);
    const float2 cs1 = *reinterpret_cast<const float2*>(rp + (size_t)258 * (i0 + 1));

    const size_t slice = (size_t)SEQL * DK;             // bh stride (elems)
    const float* xb = x + (size_t)p * DK + (q << 2);
    float* ob = out + (size_t)idx0 * 4;                 // contiguous per wave
    const size_t ostep = (size_t)NBLK * BLK * 4;        // = one bh slice

    #pragma unroll 32
    for (int k = 0; k < ITER; ++k) {
        const float4 xv = *reinterpret_cast<const float4*>(xb + (size_t)k * slice);
        vfloat4 o;
        o.x = xv.x * cs0.x - xv.y * cs0.y;
        o.y = xv.x * cs0.y + xv.y * cs0.x;
        o.z = xv.z * cs1.x - xv.w * cs1.y;
        o.w = xv.z * cs1.y + xv.w * cs1.x;
        __builtin_nontemporal_store(o, reinterpret_cast<vfloat4*>(ob + (size_t)k * ostep));
    }
}

extern "C" void kernel_launch(void* const* d_in, const int* in_sizes, int n_in,
                              void* d_out, int out_size, void* d_ws, size_t ws_size,
                              hipStream_t stream) {
    const float* x    = (const float*)d_in[0];
    const float* rope = (const float*)d_in[1];
    const int*   tp   = (const int*)d_in[2];
    float*       out  = (float*)d_out;

    rope_fused_kernel<<<NBLK, BLK, 0, stream>>>(x, rope, tp, out);
}